// Round 4
// baseline (438.239 us; speedup 1.0000x reference)
//
#include <hip/hip_runtime.h>
#include <hip/hip_bf16.h>

// Problem constants
#define BB 8
#define TT 2048
#define DD 1024   // d_model
#define FF 1024   // ff dim

typedef __attribute__((ext_vector_type(8))) short bf16x8;
typedef __attribute__((ext_vector_type(4))) float f32x4;
typedef __attribute__((ext_vector_type(4))) short s16x4;

constexpr float kScaleLog2e = 0.03125f * 1.44269504088896340736f;

__device__ __forceinline__ short bf16_bits(float x) {
    __hip_bfloat16 h = __float2bfloat16(x);
    short s;
    __builtin_memcpy(&s, &h, sizeof(short));
    return s;
}

// ---------------------------------------------------------------------------
// Merged f32 -> bf16 convert: seq (8192 blocks) + Wq/Wk/Wv (512 each).
// ---------------------------------------------------------------------------
__global__ __launch_bounds__(256) void cvt_all(
    const float* __restrict__ seq, const float* __restrict__ Wq,
    const float* __restrict__ Wk, const float* __restrict__ Wv,
    short* __restrict__ seqb, short* __restrict__ Wb)
{
    const int bid = blockIdx.x;
    const float* src;
    short* dst;
    int i;
    if (bid < 8192)      { src = seq; dst = seqb;                      i = bid * 256 + threadIdx.x; }
    else if (bid < 8704) { src = Wq;  dst = Wb;                        i = (bid - 8192) * 256 + threadIdx.x; }
    else if (bid < 9216) { src = Wk;  dst = Wb + (size_t)FF * DD;      i = (bid - 8704) * 256 + threadIdx.x; }
    else                 { src = Wv;  dst = Wb + (size_t)2 * FF * DD;  i = (bid - 9216) * 256 + threadIdx.x; }
    f32x4 a = ((const f32x4*)src)[2 * i];
    f32x4 b = ((const f32x4*)src)[2 * i + 1];
    bf16x8 o;
#pragma unroll
    for (int j = 0; j < 4; ++j) { o[j] = bf16_bits(a[j]); o[4 + j] = bf16_bits(b[j]); }
    ((bf16x8*)dst)[i] = o;
}

// ===========================================================================
// 256x256 bf16 GEMM core, round-4: round-2's ring + 2 barriers/K-tile +
// counted vmcnt(4) publishes, but NO intra-window gates: the 12 ds_reads
// and 32 MFMAs of each half-tile window are left to the COMPILER, which
// emits fine-grained per-operand lgkmcnt (m97 evidence) and interleaves
// MFMA with outstanding LDS reads — within-wave and cross-wave overlap.
// (Round-3's explicit lgkm gates + sched_barrier pinning serialized the
// LDS pipe, MFMA pipe, and staging: 6350 cyc/K-tile vs 2500 overlap floor;
// m141's lesson.)  The only fences per window are at its END:
//   sched_barrier(0); s_waitcnt lgkmcnt(0); s_waitcnt vmcnt(N); s_barrier
// lgkm(0) drains own LDS reads (slot-overwrite fence across waves);
// vmcnt(N) is the counted publish (never 0 in steady state).
//
// Ring of 4 K-half slots per operand (slot = 256r x 32k bf16 = 16 KiB;
// LDS 128 KiB).  Steady tile t:
//   W1: stage A,B(h2t+3) [4 gloads]; read k0 slots (2t)&3; 32 MFMA;
//       END: vmcnt(4) -> publishes h2t+2 (for W1(t+1)); fences slot (2t)&3
//   W2: stage A,B(h2t+4) [4 gloads]; read k1 slots (2t+1)&3; 32 MFMA;
//       END: vmcnt(4) -> publishes h2t+3 (for W2(t+1)); fences slot (2t+1)&3
// Ledger: entering t outstanding = h2t+2 (4); W1 -> 8, wait 4 drops h2t+2;
// W2 -> 8, wait 4 drops h2t+3.  In-flight gloads always target slots
// disjoint from any slot being read (distance-2 mod 4).  Tails: MODE1
// (t=T-2): W2 stages nothing, END vmcnt(0); MODE2 (t=T-1): no stages, no
// barriers.  MFMA order per acc element unchanged -> bit-identical result.
//
// Swizzle (both-sides, rule #21): chunk cp = kg ^ ((row>>1)&3); measured
// SQ_LDS_BANK_CONFLICT = 0.
// ===========================================================================
#define SLOT 8192   // shorts per K-half slot (256 rows x 32 k)

__device__ __forceinline__ void stage2(const short* g0, const short* g1,
                                       short* slot, int lo0, int lo1) {
    __builtin_amdgcn_global_load_lds(
        (const __attribute__((address_space(1))) unsigned int*)g0,
        (__attribute__((address_space(3))) unsigned int*)(slot + lo0), 16, 0, 0);
    __builtin_amdgcn_global_load_lds(
        (const __attribute__((address_space(1))) unsigned int*)g1,
        (__attribute__((address_space(3))) unsigned int*)(slot + lo1), 16, 0, 0);
}

// Window-end fence: drain own LDS reads, counted-vmcnt publish, barrier.
template<int W>
__device__ __forceinline__ void window_end() {
    __builtin_amdgcn_sched_barrier(0);
    asm volatile("s_waitcnt lgkmcnt(0)" ::: "memory");
    if constexpr (W == 4)      asm volatile("s_waitcnt vmcnt(4)" ::: "memory");
    else if constexpr (W == 0) asm volatile("s_waitcnt vmcnt(0)" ::: "memory");
    __builtin_amdgcn_s_barrier();
    __builtin_amdgcn_sched_barrier(0);
}

// One half-tile window: stage (optional) + 12 reads + 32 MFMA, compiler-
// scheduled; then fence (optional).
template<bool STAGE, int W, bool FENCE>
__device__ __forceinline__ void window(
    const short* sA, const short* sB,          // k-half slots to read
    const short* ga0, const short* ga1,        // staging sources (A,B) or null
    const short* gb0, const short* gb1,
    short* dstA, short* dstB, int lo0, int lo1,
    int wm, int wn, int rk, f32x4 (&acc)[8][4], int mo_unused)
{
    if constexpr (STAGE) {
        stage2(ga0, ga1, dstA, lo0, lo1);
        stage2(gb0, gb1, dstB, lo0, lo1);
    }
    bf16x8 a[8], b[4];
#pragma unroll
    for (int n = 0; n < 4; ++n) b[n] = *(const bf16x8*)(sB + (wn + n * 16) * 32 + rk);
#pragma unroll
    for (int m = 0; m < 8; ++m) a[m] = *(const bf16x8*)(sA + (wm + m * 16) * 32 + rk);
    __builtin_amdgcn_s_setprio(1);
#pragma unroll
    for (int m = 0; m < 8; ++m)
#pragma unroll
        for (int n = 0; n < 4; ++n)
            acc[m][n] = __builtin_amdgcn_mfma_f32_16x16x32_bf16(a[m], b[n], acc[m][n], 0, 0, 0);
    __builtin_amdgcn_s_setprio(0);
    if constexpr (FENCE) window_end<W>();
}

// MODE: 0 = steady, 1 = t==T-2 (W2 stages nothing, END vmcnt(0)),
//       2 = t==T-1 (no stages, no barriers).
template<int MODE>
__device__ __forceinline__ void tile_body(
    int t, short* As, short* Bs,
    const short* a0g, const short* a1g, const short* b0g, const short* b1g,
    int lo0, int lo1, int wm, int wn, int rk, f32x4 (&acc)[8][4])
{
    const short* sA0 = As + ((2 * t) & 3) * SLOT;
    const short* sB0 = Bs + ((2 * t) & 3) * SLOT;
    const short* sA1 = As + ((2 * t + 1) & 3) * SLOT;
    const short* sB1 = Bs + ((2 * t + 1) & 3) * SLOT;

    // W1: k-half 0; stage h2t+3
    window<(MODE <= 1), 4, (MODE <= 1)>(
        sA0, sB0,
        a0g + (2 * t + 3) * 32, a1g + (2 * t + 3) * 32,
        b0g + (2 * t + 3) * 32, b1g + (2 * t + 3) * 32,
        As + ((2 * t + 3) & 3) * SLOT, Bs + ((2 * t + 3) & 3) * SLOT,
        lo0, lo1, wm, wn, rk, acc, 0);

    // W2: k-half 1; stage h2t+4
    if constexpr (MODE == 0)
        window<true, 4, true>(
            sA1, sB1,
            a0g + (2 * t + 4) * 32, a1g + (2 * t + 4) * 32,
            b0g + (2 * t + 4) * 32, b1g + (2 * t + 4) * 32,
            As + ((2 * t + 4) & 3) * SLOT, Bs + ((2 * t + 4) & 3) * SLOT,
            lo0, lo1, wm, wn, rk, acc, 4);
    else if constexpr (MODE == 1)
        window<false, 0, true>(sA1, sB1, nullptr, nullptr, nullptr, nullptr,
                               nullptr, nullptr, lo0, lo1, wm, wn, rk, acc, 4);
    else
        window<false, 0, false>(sA1, sB1, nullptr, nullptr, nullptr, nullptr,
                                nullptr, nullptr, lo0, lo1, wm, wn, rk, acc, 4);
}

__device__ __forceinline__ void gemm256(
    const short* __restrict__ A, int lda, int m0,
    const short* __restrict__ B, int ldb, int n0,
    int T, short* As, short* Bs, f32x4 (&accA)[8][4], f32x4 (&accB)[8][4])
{
    // accA = acc rows 0-3 (M-half 0), accB = rows 4-7?  No — single acc
    // passed through two views; see caller.  (kept simple: one acc array)
    (void)accB;
    const int tid  = threadIdx.x;
    const int lane = tid & 63;
    const int w    = tid >> 6;
    const int wm   = (w >> 2) * 128;
    const int wn   = (w & 3) * 64;
    const int r    = lane & 15;
    const int qd   = lane >> 4;
    // reader swizzle: cp = qd ^ ((row>>1)&3); row = 16*frag + r -> depends on r only
    const int rk   = r * 32 + (qd ^ ((r >> 1) & 3)) * 8;

    // stage-source precompute: 16B chunk s = w*128 + j*64 + lane
    const int s0   = w * 128 + lane, s1 = s0 + 64;
    const int row0 = s0 >> 2,  row1 = s1 >> 2;
    const int cl0  = (s0 & 3) ^ ((row0 >> 1) & 3);
    const int cl1  = (s1 & 3) ^ ((row1 >> 1) & 3);
    const short* a0 = A + (size_t)(m0 + row0) * lda + cl0 * 8;
    const short* a1 = A + (size_t)(m0 + row1) * lda + cl1 * 8;
    const short* b0 = B + (size_t)(n0 + row0) * ldb + cl0 * 8;
    const short* b1 = B + (size_t)(n0 + row1) * ldb + cl1 * 8;
    const int lo0 = s0 * 8, lo1 = s1 * 8;

    // prologue: halves 0,1,2 of A and B (12 loads); vmcnt(4) -> h0,h1 landed
    stage2(a0,      a1,      As,            lo0, lo1);
    stage2(b0,      b1,      Bs,            lo0, lo1);
    stage2(a0 + 32, a1 + 32, As + SLOT,     lo0, lo1);
    stage2(b0 + 32, b1 + 32, Bs + SLOT,     lo0, lo1);
    stage2(a0 + 64, a1 + 64, As + 2 * SLOT, lo0, lo1);
    stage2(b0 + 64, b1 + 64, Bs + 2 * SLOT, lo0, lo1);
    asm volatile("s_waitcnt vmcnt(4)" ::: "memory");
    __builtin_amdgcn_s_barrier();
    __builtin_amdgcn_sched_barrier(0);

    for (int t = 0; t < T - 2; ++t)
        tile_body<0>(t, As, Bs, a0, a1, b0, b1, lo0, lo1, wm, wn, rk, accA);
    tile_body<1>(T - 2, As, Bs, a0, a1, b0, b1, lo0, lo1, wm, wn, rk, accA);
    tile_body<2>(T - 1, As, Bs, a0, a1, b0, b1, lo0, lo1, wm, wn, rk, accA);
}

// ---------------------------------------------------------------------------
// Kernel 1: q/k = seqb @ Wb^T + bias (bf16 out); v transposed vT[b][f][t].
// Grid 768 = 64 mt x 4 nt x 3 proj, XCD-chunked.
// ---------------------------------------------------------------------------
__global__ __launch_bounds__(512, 2) void qkv256(
    const short* __restrict__ seqb, const short* __restrict__ Wb,
    const float* __restrict__ bq, const float* __restrict__ bk,
    const float* __restrict__ bv,
    __hip_bfloat16* __restrict__ q, __hip_bfloat16* __restrict__ k,
    __hip_bfloat16* __restrict__ vT)
{
    __shared__ short As[4 * SLOT], Bs[4 * SLOT];
    const int bid  = blockIdx.x;
    const int id2  = (bid & 7) * 96 + (bid >> 3);   // bijective (768 % 8 == 0)
    const int mt   = id2 / 12;
    const int rest = id2 - mt * 12;
    const int nt   = rest & 3;
    const int proj = rest >> 2;

    const short* W    = Wb + (size_t)proj * FF * DD;
    const float* bias = proj == 0 ? bq : (proj == 1 ? bk : bv);

    f32x4 acc[8][4];
#pragma unroll
    for (int m = 0; m < 8; ++m)
#pragma unroll
        for (int n = 0; n < 4; ++n) acc[m][n] = (f32x4){0.f, 0.f, 0.f, 0.f};

    gemm256(seqb, DD, mt * 256, W, DD, nt * 256, DD / 64, As, Bs, acc, acc);

    const int lane = threadIdx.x & 63;
    const int w    = threadIdx.x >> 6;
    const int wm   = (w >> 2) * 128;
    const int wn   = (w & 3) * 64;
    const int r    = lane & 15;
    const int qd   = lane >> 4;
    const int row_base = mt * 256 + wm + qd * 4;
    const int col_base = nt * 256 + wn + r;

    if (proj < 2) {
        __hip_bfloat16* dst = (proj == 0) ? q : k;
#pragma unroll
        for (int nf = 0; nf < 4; ++nf) {
            const int col = col_base + nf * 16;
            const float bv_ = bias[col];
#pragma unroll
            for (int mf = 0; mf < 8; ++mf)
#pragma unroll
                for (int i = 0; i < 4; ++i)
                    dst[(size_t)(row_base + mf * 16 + i) * FF + col] =
                        __float2bfloat16(acc[mf][nf][i] + bv_);
        }
    } else {
        // transposed V: lane's 4 regs = 4 consecutive t -> 8B packed store
#pragma unroll
        for (int mf = 0; mf < 8; ++mf) {
            const int rowg = row_base + mf * 16;
            const int b_   = rowg >> 11;
            const int t_   = rowg & 2047;
            __hip_bfloat16* vb = vT + (size_t)b_ * FF * TT;
#pragma unroll
            for (int nf = 0; nf < 4; ++nf) {
                const int col = col_base + nf * 16;
                const float bvv = bias[col];
                s16x4 pack;
#pragma unroll
                for (int i = 0; i < 4; ++i) pack[i] = bf16_bits(acc[mf][nf][i] + bvv);
                *(s16x4*)(vb + (size_t)col * TT + t_) = pack;
            }
        }
    }
}

// ---------------------------------------------------------------------------
// Kernel 2: P[b][t][s] = exp(scale*q.k) bf16 (unnormalized), Z[b][t] += rowsum.
// Grid 512 = 8 b x 8 tt x 8 st (st fastest); XCD-chunked.
// ---------------------------------------------------------------------------
__global__ __launch_bounds__(512, 2) void score256(
    const __hip_bfloat16* __restrict__ q, const __hip_bfloat16* __restrict__ k,
    __hip_bfloat16* __restrict__ P, float* __restrict__ Z)
{
    __shared__ short As[4 * SLOT], Bs[4 * SLOT];
    const int bid = blockIdx.x;
    const int id2 = (bid & 7) * 64 + (bid >> 3);
    const int b   = id2 >> 6;
    const int tt  = (id2 >> 3) & 7;
    const int st  = id2 & 7;

    const short* qb = (const short*)q + (size_t)b * TT * FF;
    const short* kb = (const short*)k + (size_t)b * TT * FF;

    f32x4 acc[8][4];
#pragma unroll
    for (int m = 0; m < 8; ++m)
#pragma unroll
        for (int n = 0; n < 4; ++n) acc[m][n] = (f32x4){0.f, 0.f, 0.f, 0.f};

    gemm256(qb, FF, tt * 256, kb, FF, st * 256, FF / 64, As, Bs, acc, acc);

    const int lane = threadIdx.x & 63;
    const int w    = threadIdx.x >> 6;
    const int wm   = (w >> 2) * 128;
    const int wn   = (w & 3) * 64;
    const int r    = lane & 15;
    const int qd   = lane >> 4;
    const int row_base = tt * 256 + wm + qd * 4;
    const int col_base = st * 256 + wn + r;

    __hip_bfloat16* Pb = P + (size_t)b * TT * TT;
    float* Zb = Z + b * TT;

    float rs[8][4];
#pragma unroll
    for (int mf = 0; mf < 8; ++mf)
#pragma unroll
        for (int i = 0; i < 4; ++i) rs[mf][i] = 0.f;

#pragma unroll
    for (int mf = 0; mf < 8; ++mf)
#pragma unroll
        for (int nf = 0; nf < 4; ++nf) {
            const int col = col_base + nf * 16;
#pragma unroll
            for (int i = 0; i < 4; ++i) {
                const float e = exp2f(acc[mf][nf][i] * kScaleLog2e);
                const __hip_bfloat16 eb = __float2bfloat16(e);
                rs[mf][i] += __bfloat162float(eb);
                Pb[(size_t)(row_base + mf * 16 + i) * TT + col] = eb;
            }
        }
#pragma unroll
    for (int off = 1; off < 16; off <<= 1)
#pragma unroll
        for (int mf = 0; mf < 8; ++mf)
#pragma unroll
            for (int i = 0; i < 4; ++i) rs[mf][i] += __shfl_xor(rs[mf][i], off, 64);
    if (r == 0) {
#pragma unroll
        for (int mf = 0; mf < 8; ++mf)
#pragma unroll
            for (int i = 0; i < 4; ++i)
                atomicAdd(&Zb[row_base + mf * 16 + i], rs[mf][i]);
    }
}

// ---------------------------------------------------------------------------
// Kernel 3: out[b][t][f] = (P @ V)/Z via vT.  Grid 256 = 8 b x 8 tt x 4 ft.
// ---------------------------------------------------------------------------
__global__ __launch_bounds__(512, 2) void pv256(
    const __hip_bfloat16* __restrict__ P, const __hip_bfloat16* __restrict__ vT,
    const float* __restrict__ Z, float* __restrict__ out)
{
    __shared__ short As[4 * SLOT], Bs[4 * SLOT];
    const int bid = blockIdx.x;
    const int id2 = (bid & 7) * 32 + (bid >> 3);
    const int b   = id2 >> 5;
    const int tt  = (id2 >> 2) & 7;
    const int ft  = id2 & 3;

    const short* Pb = (const short*)P + (size_t)b * TT * TT;
    const short* vb = (const short*)vT + (size_t)b * FF * TT;

    f32x4 acc[8][4];
#pragma unroll
    for (int m = 0; m < 8; ++m)
#pragma unroll
        for (int n = 0; n < 4; ++n) acc[m][n] = (f32x4){0.f, 0.f, 0.f, 0.f};

    gemm256(Pb, TT, tt * 256, vb, TT, ft * 256, TT / 64, As, Bs, acc, acc);

    const int lane = threadIdx.x & 63;
    const int w    = threadIdx.x >> 6;
    const int wm   = (w >> 2) * 128;
    const int wn   = (w & 3) * 64;
    const int r    = lane & 15;
    const int qd   = lane >> 4;
    const int row_base = tt * 256 + wm + qd * 4;
    const int col_base = ft * 256 + wn + r;

    const float* Zb = Z + b * TT;
    float* ob = out + (size_t)b * TT * FF;

#pragma unroll
    for (int mf = 0; mf < 8; ++mf) {
        float rz[4];
#pragma unroll
        for (int i = 0; i < 4; ++i) rz[i] = 1.0f / Zb[row_base + mf * 16 + i];
#pragma unroll
        for (int nf = 0; nf < 4; ++nf) {
            const int col = col_base + nf * 16;
#pragma unroll
            for (int i = 0; i < 4; ++i)
                ob[(size_t)(row_base + mf * 16 + i) * FF + col] = acc[mf][nf][i] * rz[i];
        }
    }
}

// ---------------------------------------------------------------------------
extern "C" void kernel_launch(void* const* d_in, const int* in_sizes, int n_in,
                              void* d_out, int out_size, void* d_ws, size_t ws_size,
                              hipStream_t stream) {
    const float* seq = (const float*)d_in[0];
    const float* Wq  = (const float*)d_in[1];
    const float* bq  = (const float*)d_in[2];
    const float* Wk  = (const float*)d_in[3];
    const float* bk  = (const float*)d_in[4];
    const float* Wv  = (const float*)d_in[5];
    const float* bv  = (const float*)d_in[6];
    float* out = (float*)d_out;
    char* ws = (char*)d_ws;

    // Workspace layout (unchanged):
    //   q   : 32 MiB @ 0
    //   k   : 32 MiB @ 33554432
    //   vT  : 32 MiB @ 67108864
    //   P   : 64 MiB @ 100663296   (seqb [32 MiB] + Wb [6 MiB] alias P;
    //                               both dead before score writes P)
    //   Z   : 64 KiB @ 167772160
    const size_t MB32 = 33554432;
    __hip_bfloat16* q   = (__hip_bfloat16*)(ws);
    __hip_bfloat16* k   = (__hip_bfloat16*)(ws + MB32);
    __hip_bfloat16* vT  = (__hip_bfloat16*)(ws + 2 * MB32);
    __hip_bfloat16* P   = (__hip_bfloat16*)(ws + 3 * MB32);
    float*          Z   = (float*)(ws + 3 * MB32 + (size_t)67108864);
    short*          seqb = (short*)P;
    short*          Wb   = (short*)((char*)P + MB32);

    hipMemsetAsync(Z, 0, (size_t)BB * TT * sizeof(float), stream);

    cvt_all<<<9728, 256, 0, stream>>>(seq, Wq, Wk, Wv, seqb, Wb);
    qkv256<<<768, 512, 0, stream>>>(seqb, Wb, bq, bk, bv, q, k, vT);
    score256<<<BB * 64, 512, 0, stream>>>(q, k, P, Z);
    pv256<<<BB * 32, 512, 0, stream>>>(P, vT, Z, out);
}

// Round 5
// 406.601 us; speedup vs baseline: 1.0778x; 1.0778x over previous
//
#include <hip/hip_runtime.h>
#include <hip/hip_bf16.h>

// Problem constants
#define BB 8
#define TT 2048
#define DD 1024   // d_model
#define FF 1024   // ff dim

typedef __attribute__((ext_vector_type(8))) short bf16x8;
typedef __attribute__((ext_vector_type(4))) float f32x4;
typedef __attribute__((ext_vector_type(4))) short s16x4;

constexpr float kScaleLog2e = 0.03125f * 1.44269504088896340736f;

__device__ __forceinline__ short bf16_bits(float x) {
    __hip_bfloat16 h = __float2bfloat16(x);
    short s;
    __builtin_memcpy(&s, &h, sizeof(short));
    return s;
}

// ---------------------------------------------------------------------------
// Merged f32 -> bf16 convert: seq (8192 blocks) + Wq/Wk/Wv (512 each).
// ---------------------------------------------------------------------------
__global__ __launch_bounds__(256) void cvt_all(
    const float* __restrict__ seq, const float* __restrict__ Wq,
    const float* __restrict__ Wk, const float* __restrict__ Wv,
    short* __restrict__ seqb, short* __restrict__ Wb)
{
    const int bid = blockIdx.x;
    const float* src;
    short* dst;
    int i;
    if (bid < 8192)      { src = seq; dst = seqb;                      i = bid * 256 + threadIdx.x; }
    else if (bid < 8704) { src = Wq;  dst = Wb;                        i = (bid - 8192) * 256 + threadIdx.x; }
    else if (bid < 9216) { src = Wk;  dst = Wb + (size_t)FF * DD;      i = (bid - 8704) * 256 + threadIdx.x; }
    else                 { src = Wv;  dst = Wb + (size_t)2 * FF * DD;  i = (bid - 9216) * 256 + threadIdx.x; }
    f32x4 a = ((const f32x4*)src)[2 * i];
    f32x4 b = ((const f32x4*)src)[2 * i + 1];
    bf16x8 o;
#pragma unroll
    for (int j = 0; j < 4; ++j) { o[j] = bf16_bits(a[j]); o[4 + j] = bf16_bits(b[j]); }
    ((bf16x8*)dst)[i] = o;
}

// ===========================================================================
// 256x256 bf16 GEMM core, round-5: faithful m201 8-phase cadence.
//
// Units: 16-KiB slabs (256 rows x 32 k).  Slots: A buf0 {As+0, As+S},
// buf1 {As+2S, As+3S}; same for Bs (128 KiB total).  Iter i reads K-tiles
// t0=2i (buf0, ph1-4) and t1=2i+1 (buf1, ph5-8); ONE stage per phase:
//   ph1: A(2i+1)ks0   ph2: A(2i+1)ks1   ph3: B(2i+2)ks0   ph4: B(2i+2)ks1
//   ph5: A(2i+2)ks0   ph6: A(2i+2)ks1   ph7: B(2i+3)ks0   ph8: B(2i+3)ks1
// Waits: vmcnt(4) after ph4 MFMA (drains thru ph2 -> tile 2i+1 complete
// before ph5 reads) and after ph8 (drains thru ph6 -> tile 2i+2 complete
// before next-iter ph1).  Never 0 in steady state.
// Overwrite-safety (all verified): each stage issues >=1 closing-barrier
// after its slot's last reader phase (B-buf0 last read ph2 -> staged ph3;
// A-buf0 last read ph3 -> ph5; B-buf1 last read ph6 -> ph7; A-buf1 last
// read ph7 -> ph1 next iter).  Closing barrier = cross-wave read fence
// (each wave's reads retire at its own lgkm(0) before its MFMA).
// Phase shape (m201): reads+stage | sched_barrier | s_barrier | lgkm(0) |
// sched_barrier | setprio(1) | 16 MFMA (one C-quadrant x K=64) |
// setprio(0) | [vmcnt] | s_barrier | sched_barrier.  The pre-barrier read
// issue + post-barrier lgkm(0) creates per-phase wave stagger: LDS FIFO
// releases waves into the MFMA pipe one at a time -> pipes overlap.
// Prologue: tile0 (4 units) + B(1) (2 units) = 12 loads, vmcnt(4), barrier.
// Last iter: stages only ph1/ph2 (A(T-1)); ph4 vmcnt(0); ph8 bare.
// MFMA per-acc-element order unchanged (tiles asc, ksub asc) -> result
// bit-identical to rounds 0-4.
// Swizzle (both-sides, rule #21) unchanged; SQ_LDS_BANK_CONFLICT == 0.
// ===========================================================================
#define SLOT 8192   // shorts per slab (256 rows x 32 k)

__device__ __forceinline__ void stage2(const short* g0, const short* g1,
                                       short* slot, int lo0, int lo1) {
    __builtin_amdgcn_global_load_lds(
        (const __attribute__((address_space(1))) unsigned int*)g0,
        (__attribute__((address_space(3))) unsigned int*)(slot + lo0), 16, 0, 0);
    __builtin_amdgcn_global_load_lds(
        (const __attribute__((address_space(1))) unsigned int*)g1,
        (__attribute__((address_space(3))) unsigned int*)(slot + lo1), 16, 0, 0);
}

__device__ __forceinline__ void ph_open() {
    __builtin_amdgcn_sched_barrier(0);          // pin reads+stage above barrier
    __builtin_amdgcn_s_barrier();
    asm volatile("s_waitcnt lgkmcnt(0)" ::: "memory");
    __builtin_amdgcn_sched_barrier(0);          // rule #18
    __builtin_amdgcn_s_setprio(1);
}

__device__ __forceinline__ void ph_close() {
    __builtin_amdgcn_s_setprio(0);
    __builtin_amdgcn_sched_barrier(0);
    __builtin_amdgcn_s_barrier();               // cross-wave read fence
    __builtin_amdgcn_sched_barrier(0);
}

#define MFMA_Q(MO, NO)                                                        \
_Pragma("unroll")                                                             \
    for (int mm = 0; mm < 4; ++mm)                                            \
_Pragma("unroll")                                                             \
        for (int nn = NO; nn < NO + 2; ++nn) {                                \
            acc[MO + mm][nn] = __builtin_amdgcn_mfma_f32_16x16x32_bf16(       \
                a[mm][0], b[nn][0], acc[MO + mm][nn], 0, 0, 0);               \
            acc[MO + mm][nn] = __builtin_amdgcn_mfma_f32_16x16x32_bf16(       \
                a[mm][1], b[nn][1], acc[MO + mm][nn], 0, 0, 0);               \
        }

template<bool FULL>
__device__ __forceinline__ void iter8(
    int i, short* As, short* Bs,
    const short* a0, const short* a1, const short* b0, const short* b1,
    int lo0, int lo1, int wm, int wn, int rk, f32x4 (&acc)[8][4])
{
    bf16x8 a[4][2], b[4][2];
    const int h = 4 * i;

    // ---- ph1: read A[t0][mh0]+B[t0][nh0] (12); stage A(2i+1)ks0 ----
#pragma unroll
    for (int m = 0; m < 4; ++m) {
        a[m][0] = *(const bf16x8*)(As + (wm + m * 16) * 32 + rk);
        a[m][1] = *(const bf16x8*)(As + SLOT + (wm + m * 16) * 32 + rk);
    }
#pragma unroll
    for (int n = 0; n < 2; ++n) {
        b[n][0] = *(const bf16x8*)(Bs + (wn + n * 16) * 32 + rk);
        b[n][1] = *(const bf16x8*)(Bs + SLOT + (wn + n * 16) * 32 + rk);
    }
    stage2(a0 + (h + 2) * 32, a1 + (h + 2) * 32, As + 2 * SLOT, lo0, lo1);
    ph_open();
    MFMA_Q(0, 0)
    ph_close();

    // ---- ph2: read B[t0][nh1] (4); stage A(2i+1)ks1 ----
#pragma unroll
    for (int n = 2; n < 4; ++n) {
        b[n][0] = *(const bf16x8*)(Bs + (wn + n * 16) * 32 + rk);
        b[n][1] = *(const bf16x8*)(Bs + SLOT + (wn + n * 16) * 32 + rk);
    }
    stage2(a0 + (h + 3) * 32, a1 + (h + 3) * 32, As + 3 * SLOT, lo0, lo1);
    ph_open();
    MFMA_Q(0, 2)
    ph_close();

    // ---- ph3: read A[t0][mh1] (8); stage B(2i+2)ks0 ----
#pragma unroll
    for (int m = 0; m < 4; ++m) {
        a[m][0] = *(const bf16x8*)(As + (wm + 64 + m * 16) * 32 + rk);
        a[m][1] = *(const bf16x8*)(As + SLOT + (wm + 64 + m * 16) * 32 + rk);
    }
    if constexpr (FULL) stage2(b0 + (h + 4) * 32, b1 + (h + 4) * 32, Bs, lo0, lo1);
    ph_open();
    MFMA_Q(4, 0)
    ph_close();

    // ---- ph4: no reads; stage B(2i+2)ks1; vmcnt(4)/(0) ----
    if constexpr (FULL) stage2(b0 + (h + 5) * 32, b1 + (h + 5) * 32, Bs + SLOT, lo0, lo1);
    ph_open();
    MFMA_Q(4, 2)
    __builtin_amdgcn_s_setprio(0);
    __builtin_amdgcn_sched_barrier(0);
    if constexpr (FULL) asm volatile("s_waitcnt vmcnt(4)" ::: "memory");
    else                asm volatile("s_waitcnt vmcnt(0)" ::: "memory");
    __builtin_amdgcn_s_barrier();
    __builtin_amdgcn_sched_barrier(0);

    // ---- ph5: read A[t1][mh0]+B[t1][nh0] (12); stage A(2i+2)ks0 ----
#pragma unroll
    for (int m = 0; m < 4; ++m) {
        a[m][0] = *(const bf16x8*)(As + 2 * SLOT + (wm + m * 16) * 32 + rk);
        a[m][1] = *(const bf16x8*)(As + 3 * SLOT + (wm + m * 16) * 32 + rk);
    }
#pragma unroll
    for (int n = 0; n < 2; ++n) {
        b[n][0] = *(const bf16x8*)(Bs + 2 * SLOT + (wn + n * 16) * 32 + rk);
        b[n][1] = *(const bf16x8*)(Bs + 3 * SLOT + (wn + n * 16) * 32 + rk);
    }
    if constexpr (FULL) stage2(a0 + (h + 4) * 32, a1 + (h + 4) * 32, As, lo0, lo1);
    ph_open();
    MFMA_Q(0, 0)
    ph_close();

    // ---- ph6: read B[t1][nh1] (4); stage A(2i+2)ks1 ----
#pragma unroll
    for (int n = 2; n < 4; ++n) {
        b[n][0] = *(const bf16x8*)(Bs + 2 * SLOT + (wn + n * 16) * 32 + rk);
        b[n][1] = *(const bf16x8*)(Bs + 3 * SLOT + (wn + n * 16) * 32 + rk);
    }
    if constexpr (FULL) stage2(a0 + (h + 5) * 32, a1 + (h + 5) * 32, As + SLOT, lo0, lo1);
    ph_open();
    MFMA_Q(0, 2)
    ph_close();

    // ---- ph7: read A[t1][mh1] (8); stage B(2i+3)ks0 ----
#pragma unroll
    for (int m = 0; m < 4; ++m) {
        a[m][0] = *(const bf16x8*)(As + 2 * SLOT + (wm + 64 + m * 16) * 32 + rk);
        a[m][1] = *(const bf16x8*)(As + 3 * SLOT + (wm + 64 + m * 16) * 32 + rk);
    }
    if constexpr (FULL) stage2(b0 + (h + 6) * 32, b1 + (h + 6) * 32, Bs + 2 * SLOT, lo0, lo1);
    ph_open();
    MFMA_Q(4, 0)
    ph_close();

    // ---- ph8: no reads; stage B(2i+3)ks1; FULL: vmcnt(4)+barrier ----
    if constexpr (FULL) stage2(b0 + (h + 7) * 32, b1 + (h + 7) * 32, Bs + 3 * SLOT, lo0, lo1);
    ph_open();
    MFMA_Q(4, 2)
    __builtin_amdgcn_s_setprio(0);
    __builtin_amdgcn_sched_barrier(0);
    if constexpr (FULL) {
        asm volatile("s_waitcnt vmcnt(4)" ::: "memory");
        __builtin_amdgcn_s_barrier();
        __builtin_amdgcn_sched_barrier(0);
    }
}

__device__ __forceinline__ void gemm256(
    const short* __restrict__ A, int lda, int m0,
    const short* __restrict__ B, int ldb, int n0,
    int T, short* As, short* Bs, f32x4 (&acc)[8][4])
{
    const int tid  = threadIdx.x;
    const int lane = tid & 63;
    const int w    = tid >> 6;
    const int wm   = (w >> 2) * 128;
    const int wn   = (w & 3) * 64;
    const int r    = lane & 15;
    const int qd   = lane >> 4;
    // reader swizzle: cp = qd ^ ((row>>1)&3)
    const int rk   = r * 32 + (qd ^ ((r >> 1) & 3)) * 8;

    // stage-source precompute: 16B chunk s = w*128 + j*64 + lane
    const int s0   = w * 128 + lane, s1 = s0 + 64;
    const int row0 = s0 >> 2,  row1 = s1 >> 2;
    const int cl0  = (s0 & 3) ^ ((row0 >> 1) & 3);
    const int cl1  = (s1 & 3) ^ ((row1 >> 1) & 3);
    const short* a0 = A + (size_t)(m0 + row0) * lda + cl0 * 8;
    const short* a1 = A + (size_t)(m0 + row1) * lda + cl1 * 8;
    const short* b0 = B + (size_t)(n0 + row0) * ldb + cl0 * 8;
    const short* b1 = B + (size_t)(n0 + row1) * ldb + cl1 * 8;
    const int lo0 = s0 * 8, lo1 = s1 * 8;

    // prologue: tile0 (A,B) into buf0 + B(1) into buf1 = 12 loads;
    // vmcnt(4) -> tile0 landed, B(1) (4 loads) in flight = steady entry.
    stage2(a0,      a1,      As,            lo0, lo1);   // A0 ks0
    stage2(a0 + 32, a1 + 32, As + SLOT,     lo0, lo1);   // A0 ks1
    stage2(b0,      b1,      Bs,            lo0, lo1);   // B0 ks0
    stage2(b0 + 32, b1 + 32, Bs + SLOT,     lo0, lo1);   // B0 ks1
    stage2(b0 + 64, b1 + 64, Bs + 2 * SLOT, lo0, lo1);   // B1 ks0
    stage2(b0 + 96, b1 + 96, Bs + 3 * SLOT, lo0, lo1);   // B1 ks1
    asm volatile("s_waitcnt vmcnt(4)" ::: "memory");
    __builtin_amdgcn_s_barrier();
    __builtin_amdgcn_sched_barrier(0);

    const int NI = T / 2;
    for (int i = 0; i < NI - 1; ++i)
        iter8<true>(i, As, Bs, a0, a1, b0, b1, lo0, lo1, wm, wn, rk, acc);
    iter8<false>(NI - 1, As, Bs, a0, a1, b0, b1, lo0, lo1, wm, wn, rk, acc);
}

// ---------------------------------------------------------------------------
// Kernel 1: q/k = seqb @ Wb^T + bias (bf16 out); v transposed vT[b][f][t].
// Grid 768 = 64 mt x 4 nt x 3 proj, XCD-chunked.
// ---------------------------------------------------------------------------
__global__ __launch_bounds__(512, 2) void qkv256(
    const short* __restrict__ seqb, const short* __restrict__ Wb,
    const float* __restrict__ bq, const float* __restrict__ bk,
    const float* __restrict__ bv,
    __hip_bfloat16* __restrict__ q, __hip_bfloat16* __restrict__ k,
    __hip_bfloat16* __restrict__ vT)
{
    __shared__ short As[4 * SLOT], Bs[4 * SLOT];
    const int bid  = blockIdx.x;
    const int id2  = (bid & 7) * 96 + (bid >> 3);   // bijective (768 % 8 == 0)
    const int mt   = id2 / 12;
    const int rest = id2 - mt * 12;
    const int nt   = rest & 3;
    const int proj = rest >> 2;

    const short* W    = Wb + (size_t)proj * FF * DD;
    const float* bias = proj == 0 ? bq : (proj == 1 ? bk : bv);

    f32x4 acc[8][4];
#pragma unroll
    for (int m = 0; m < 8; ++m)
#pragma unroll
        for (int n = 0; n < 4; ++n) acc[m][n] = (f32x4){0.f, 0.f, 0.f, 0.f};

    gemm256(seqb, DD, mt * 256, W, DD, nt * 256, DD / 64, As, Bs, acc);

    const int lane = threadIdx.x & 63;
    const int w    = threadIdx.x >> 6;
    const int wm   = (w >> 2) * 128;
    const int wn   = (w & 3) * 64;
    const int r    = lane & 15;
    const int qd   = lane >> 4;
    const int row_base = mt * 256 + wm + qd * 4;
    const int col_base = nt * 256 + wn + r;

    if (proj < 2) {
        __hip_bfloat16* dst = (proj == 0) ? q : k;
#pragma unroll
        for (int nf = 0; nf < 4; ++nf) {
            const int col = col_base + nf * 16;
            const float bv_ = bias[col];
#pragma unroll
            for (int mf = 0; mf < 8; ++mf)
#pragma unroll
                for (int i = 0; i < 4; ++i)
                    dst[(size_t)(row_base + mf * 16 + i) * FF + col] =
                        __float2bfloat16(acc[mf][nf][i] + bv_);
        }
    } else {
        // transposed V: lane's 4 regs = 4 consecutive t -> 8B packed store
#pragma unroll
        for (int mf = 0; mf < 8; ++mf) {
            const int rowg = row_base + mf * 16;
            const int b_   = rowg >> 11;
            const int t_   = rowg & 2047;
            __hip_bfloat16* vb = vT + (size_t)b_ * FF * TT;
#pragma unroll
            for (int nf = 0; nf < 4; ++nf) {
                const int col = col_base + nf * 16;
                const float bvv = bias[col];
                s16x4 pack;
#pragma unroll
                for (int i = 0; i < 4; ++i) pack[i] = bf16_bits(acc[mf][nf][i] + bvv);
                *(s16x4*)(vb + (size_t)col * TT + t_) = pack;
            }
        }
    }
}

// ---------------------------------------------------------------------------
// Kernel 2: P[b][t][s] = exp(scale*q.k) bf16 (unnormalized), Z[b][t] += rowsum.
// Grid 512 = 8 b x 8 tt x 8 st (st fastest); XCD-chunked.
// ---------------------------------------------------------------------------
__global__ __launch_bounds__(512, 2) void score256(
    const __hip_bfloat16* __restrict__ q, const __hip_bfloat16* __restrict__ k,
    __hip_bfloat16* __restrict__ P, float* __restrict__ Z)
{
    __shared__ short As[4 * SLOT], Bs[4 * SLOT];
    const int bid = blockIdx.x;
    const int id2 = (bid & 7) * 64 + (bid >> 3);
    const int b   = id2 >> 6;
    const int tt  = (id2 >> 3) & 7;
    const int st  = id2 & 7;

    const short* qb = (const short*)q + (size_t)b * TT * FF;
    const short* kb = (const short*)k + (size_t)b * TT * FF;

    f32x4 acc[8][4];
#pragma unroll
    for (int m = 0; m < 8; ++m)
#pragma unroll
        for (int n = 0; n < 4; ++n) acc[m][n] = (f32x4){0.f, 0.f, 0.f, 0.f};

    gemm256(qb, FF, tt * 256, kb, FF, st * 256, FF / 64, As, Bs, acc);

    const int lane = threadIdx.x & 63;
    const int w    = threadIdx.x >> 6;
    const int wm   = (w >> 2) * 128;
    const int wn   = (w & 3) * 64;
    const int r    = lane & 15;
    const int qd   = lane >> 4;
    const int row_base = tt * 256 + wm + qd * 4;
    const int col_base = st * 256 + wn + r;

    __hip_bfloat16* Pb = P + (size_t)b * TT * TT;
    float* Zb = Z + b * TT;

    float rs[8][4];
#pragma unroll
    for (int mf = 0; mf < 8; ++mf)
#pragma unroll
        for (int i = 0; i < 4; ++i) rs[mf][i] = 0.f;

#pragma unroll
    for (int mf = 0; mf < 8; ++mf)
#pragma unroll
        for (int nf = 0; nf < 4; ++nf) {
            const int col = col_base + nf * 16;
#pragma unroll
            for (int i = 0; i < 4; ++i) {
                const float e = exp2f(acc[mf][nf][i] * kScaleLog2e);
                const __hip_bfloat16 eb = __float2bfloat16(e);
                rs[mf][i] += __bfloat162float(eb);
                Pb[(size_t)(row_base + mf * 16 + i) * TT + col] = eb;
            }
        }
#pragma unroll
    for (int off = 1; off < 16; off <<= 1)
#pragma unroll
        for (int mf = 0; mf < 8; ++mf)
#pragma unroll
            for (int i = 0; i < 4; ++i) rs[mf][i] += __shfl_xor(rs[mf][i], off, 64);
    if (r == 0) {
#pragma unroll
        for (int mf = 0; mf < 8; ++mf)
#pragma unroll
            for (int i = 0; i < 4; ++i)
                atomicAdd(&Zb[row_base + mf * 16 + i], rs[mf][i]);
    }
}

// ---------------------------------------------------------------------------
// Kernel 3: out[b][t][f] = (P @ V)/Z via vT.  Grid 256 = 8 b x 8 tt x 4 ft.
// ---------------------------------------------------------------------------
__global__ __launch_bounds__(512, 2) void pv256(
    const __hip_bfloat16* __restrict__ P, const __hip_bfloat16* __restrict__ vT,
    const float* __restrict__ Z, float* __restrict__ out)
{
    __shared__ short As[4 * SLOT], Bs[4 * SLOT];
    const int bid = blockIdx.x;
    const int id2 = (bid & 7) * 32 + (bid >> 3);
    const int b   = id2 >> 5;
    const int tt  = (id2 >> 2) & 7;
    const int ft  = id2 & 3;

    const short* Pb = (const short*)P + (size_t)b * TT * TT;
    const short* vb = (const short*)vT + (size_t)b * FF * TT;

    f32x4 acc[8][4];
#pragma unroll
    for (int m = 0; m < 8; ++m)
#pragma unroll
        for (int n = 0; n < 4; ++n) acc[m][n] = (f32x4){0.f, 0.f, 0.f, 0.f};

    gemm256(Pb, TT, tt * 256, vb, TT, ft * 256, TT / 64, As, Bs, acc);

    const int lane = threadIdx.x & 63;
    const int w    = threadIdx.x >> 6;
    const int wm   = (w >> 2) * 128;
    const int wn   = (w & 3) * 64;
    const int r    = lane & 15;
    const int qd   = lane >> 4;
    const int row_base = tt * 256 + wm + qd * 4;
    const int col_base = ft * 256 + wn + r;

    const float* Zb = Z + b * TT;
    float* ob = out + (size_t)b * TT * FF;

#pragma unroll
    for (int mf = 0; mf < 8; ++mf) {
        float rz[4];
#pragma unroll
        for (int i = 0; i < 4; ++i) rz[i] = 1.0f / Zb[row_base + mf * 16 + i];
#pragma unroll
        for (int nf = 0; nf < 4; ++nf) {
            const int col = col_base + nf * 16;
#pragma unroll
            for (int i = 0; i < 4; ++i)
                ob[(size_t)(row_base + mf * 16 + i) * FF + col] = acc[mf][nf][i] * rz[i];
        }
    }
}

// ---------------------------------------------------------------------------
extern "C" void kernel_launch(void* const* d_in, const int* in_sizes, int n_in,
                              void* d_out, int out_size, void* d_ws, size_t ws_size,
                              hipStream_t stream) {
    const float* seq = (const float*)d_in[0];
    const float* Wq  = (const float*)d_in[1];
    const float* bq  = (const float*)d_in[2];
    const float* Wk  = (const float*)d_in[3];
    const float* bk  = (const float*)d_in[4];
    const float* Wv  = (const float*)d_in[5];
    const float* bv  = (const float*)d_in[6];
    float* out = (float*)d_out;
    char* ws = (char*)d_ws;

    // Workspace layout (unchanged):
    //   q   : 32 MiB @ 0
    //   k   : 32 MiB @ 33554432
    //   vT  : 32 MiB @ 67108864
    //   P   : 64 MiB @ 100663296   (seqb [32 MiB] + Wb [6 MiB] alias P;
    //                               both dead before score writes P)
    //   Z   : 64 KiB @ 167772160
    const size_t MB32 = 33554432;
    __hip_bfloat16* q   = (__hip_bfloat16*)(ws);
    __hip_bfloat16* k   = (__hip_bfloat16*)(ws + MB32);
    __hip_bfloat16* vT  = (__hip_bfloat16*)(ws + 2 * MB32);
    __hip_bfloat16* P   = (__hip_bfloat16*)(ws + 3 * MB32);
    float*          Z   = (float*)(ws + 3 * MB32 + (size_t)67108864);
    short*          seqb = (short*)P;
    short*          Wb   = (short*)((char*)P + MB32);

    hipMemsetAsync(Z, 0, (size_t)BB * TT * sizeof(float), stream);

    cvt_all<<<9728, 256, 0, stream>>>(seq, Wq, Wk, Wv, seqb, Wb);
    qkv256<<<768, 512, 0, stream>>>(seqb, Wb, bq, bk, bv, q, k, vT);
    score256<<<BB * 64, 512, 0, stream>>>(q, k, P, Z);
    pv256<<<BB * 32, 512, 0, stream>>>(P, vT, Z, out);
}